// Round 6
// baseline (461.844 us; speedup 1.0000x reference)
//
#include <hip/hip_runtime.h>
#include <math.h>

// Shapes fixed by the reference's setup_inputs()
#define B_ 4
#define N_ 8192
#define M_ 8192
#define O_ 32
#define E_ 128
#define F_ 128
#define K_ 8

#define LOG_HALF_F (-0.6931471805599453f)
#define GUARD_F 1e-7f

typedef float f4v __attribute__((ext_vector_type(4)));

// One 128-thread block (2 waves) per (b, m) pair.
// __launch_bounds__(128, 8): 8 waves/EU -> 16 blocks/CU (VGPR cap 64; we use ~40).
__global__ __launch_bounds__(128, 8) void n3agg_kernel(
    const float* __restrict__ x,        // (B,N,F)
    const float* __restrict__ xe,       // (B,N,E)
    const float* __restrict__ ye,       // (B,M,E)
    const float* __restrict__ log_temp, // (1,)
    const int*   __restrict__ I,        // (B,M,O)
    float*       __restrict__ out)      // (B,M,F,K)
{
    __shared__ float s_logits[O_];
    __shared__ float s_W[O_ * K_];   // [o][k]: 2x ds_read_b128 broadcast per o

    const int t   = threadIdx.x;
    // XCD-batch swizzle: blocks are dispatched round-robin to the 8 XCDs
    // (XCD = blockIdx.x % 8). Map so each XCD works one contiguous 4096-m
    // slice of ONE batch -> per-XCD L2 hot set = that batch's x+xe (8.4 MB)
    // instead of all four batches (33.6 MB). 32768 % 8 == 0 -> bijective.
    const int bid = blockIdx.x;
    const int bm  = ((bid & 7) << 12) | (bid >> 3);   // b*M + m
    const int b   = bm >> 13;                          // / M_

    const float inv_temp = 1.0f / expf(log_temp[0]);

    // ---- distance phase: 32 groups x 4 lanes, contiguous per-group access ----
    // lane l of group g reads float4 at element offset (j*4+l)*4: the 4 lanes
    // cover 64 contiguous bytes per j -> dense cache lines, each touched once.
    {
        const int g = t >> 2;   // candidate o (0..31 across the 2 waves)
        const int l = t & 3;    // lane within group
        const int idxg = I[(size_t)bm * O_ + g];
        const float4* yrow = (const float4*)(ye + (size_t)bm * E_);
        const float4* xrow = (const float4*)(xe + ((size_t)b * N_ + idxg) * E_);
        float acc = 0.f;
        #pragma unroll
        for (int j = 0; j < 8; ++j) {
            float4 yv = yrow[j * 4 + l];
            float4 xv = xrow[j * 4 + l];
            float d0 = xv.x - yv.x, d1 = xv.y - yv.y;
            float d2 = xv.z - yv.z, d3 = xv.w - yv.w;
            acc += d0 * d0 + d1 * d1 + d2 * d2 + d3 * d3;
        }
        acc += __shfl_xor(acc, 1);
        acc += __shfl_xor(acc, 2);
        if (l == 0) s_logits[g] = -acc * inv_temp;   // D / temperature
    }

    // ---- prefetch ALL 32 gathered x values (thread t owns f=t). ----
    // Irow is block-uniform -> SGPR loads. asm pins keep the loads HERE so
    // the gather latency hides under the softmax (r4: compiler sank them).
    const int* Irow = I + (size_t)bm * O_;
    const float* xb = x + (size_t)b * (N_ * F_) + t;
    float xv[O_];
    #pragma unroll
    for (int o = 0; o < O_; ++o) {
        xv[o] = xb[(size_t)(Irow[o] * F_)];
    }
    #pragma unroll
    for (int o = 0; o < O_; ++o) {
        asm volatile("" : "+v"(xv[o]));   // keep live across softmax, no code
    }

    __syncthreads();   // s_logits ready

    // ---- K-step relaxed top-k softmax: wave 0, lanes 0..31 (one lane per o) ----
    if (t < O_) {
        float logit = s_logits[t];
        float wloc[K_];
        #pragma unroll
        for (int k = 0; k < K_; ++k) {
            float mx = logit;
            #pragma unroll
            for (int d = 16; d >= 1; d >>= 1) mx = fmaxf(mx, __shfl_xor(mx, d, 32));
            float sh = logit - mx;
            float ev = __expf(sh);
            float sm = ev;
            #pragma unroll
            for (int d = 16; d >= 1; d >>= 1) sm += __shfl_xor(sm, d, 32);
            // sh=0 at the max lane -> sm >= 1 exactly -> w <= 0 -> Taylor p <= 0
            // -> arg = GUARD - p > 0 always (no NaN branch with fast log).
            float w = sh - __logf(sm);
            float sample = __expf(w);
            wloc[k] = sample;
            // log1mexp(w), reference branch + guard semantics:
            //  w <  log(0.5): log1p(-exp(w)) == log(1 - sample), no cancellation
            //  w >= log(0.5): log(-expm1(w) + 1e-7), expm1 via deg-7 Taylor
            float p = w * (1.0f + w * (0.5f + w * (0.16666667f + w * (4.1666667e-2f
                    + w * (8.3333333e-3f + w * (1.3888889e-3f + w * 1.9841270e-4f))))));
            float arg = (w < LOG_HALF_F) ? (1.0f - sample) : (GUARD_F - p);
            logit += __logf(arg);
        }
        ((float4*)&s_W[t * K_])[0] = make_float4(wloc[0], wloc[1], wloc[2], wloc[3]);
        ((float4*)&s_W[t * K_])[1] = make_float4(wloc[4], wloc[5], wloc[6], wloc[7]);
    }
    __syncthreads();   // s_W ready

    // ---- aggregation: thread t owns f = t; W via LDS broadcast, x from regs ----
    {
        float acc[K_];
        #pragma unroll
        for (int k = 0; k < K_; ++k) acc[k] = 0.f;
        #pragma unroll
        for (int o = 0; o < O_; ++o) {
            const float4 w0 = ((const float4*)&s_W[o * K_])[0];
            const float4 w1 = ((const float4*)&s_W[o * K_])[1];
            const float xvo = xv[o];
            acc[0] = fmaf(xvo, w0.x, acc[0]);
            acc[1] = fmaf(xvo, w0.y, acc[1]);
            acc[2] = fmaf(xvo, w0.z, acc[2]);
            acc[3] = fmaf(xvo, w0.w, acc[3]);
            acc[4] = fmaf(xvo, w1.x, acc[4]);
            acc[5] = fmaf(xvo, w1.y, acc[5]);
            acc[6] = fmaf(xvo, w1.z, acc[6]);
            acc[7] = fmaf(xvo, w1.w, acc[7]);
        }
        // Output is write-once, never re-read: nontemporal keeps it out of L2
        // so the gather working set (x/xe rows) stays cached.
        float* orow = out + ((size_t)bm * F_ + t) * K_;
        f4v o0 = {acc[0], acc[1], acc[2], acc[3]};
        f4v o1 = {acc[4], acc[5], acc[6], acc[7]};
        __builtin_nontemporal_store(o0, (f4v*)orow);
        __builtin_nontemporal_store(o1, (f4v*)(orow + 4));
    }
}

extern "C" void kernel_launch(void* const* d_in, const int* in_sizes, int n_in,
                              void* d_out, int out_size, void* d_ws, size_t ws_size,
                              hipStream_t stream) {
    const float* x        = (const float*)d_in[0];
    const float* xe       = (const float*)d_in[1];
    const float* ye       = (const float*)d_in[2];
    const float* log_temp = (const float*)d_in[3];
    const int*   I        = (const int*)d_in[4];
    float* out = (float*)d_out;

    dim3 grid(B_ * M_);
    dim3 block(128);
    hipLaunchKernelGGL(n3agg_kernel, grid, block, 0, stream,
                       x, xe, ye, log_temp, I, out);
}

// Round 7
// 212.431 us; speedup vs baseline: 2.1741x; 2.1741x over previous
//
#include <hip/hip_runtime.h>
#include <math.h>

// Shapes fixed by the reference's setup_inputs()
#define B_ 4
#define N_ 8192
#define M_ 8192
#define O_ 32
#define E_ 128
#define F_ 128
#define K_ 8

#define LOG_HALF_F (-0.6931471805599453f)
#define GUARD_F 1e-7f

// One 128-thread block (2 waves) per (b, m) pair.
// __launch_bounds__(128, 6): 6 waves/EU -> 12 blocks/CU, VGPR cap ~84.
// DO NOT raise to (128,8): the 64-VGPR cap spills the pinned xv[32] array
// to scratch (+~1 GB of HBM traffic, 3x slowdown — measured round 6).
__global__ __launch_bounds__(128, 6) void n3agg_kernel(
    const float* __restrict__ x,        // (B,N,F)
    const float* __restrict__ xe,       // (B,N,E)
    const float* __restrict__ ye,       // (B,M,E)
    const float* __restrict__ log_temp, // (1,)
    const int*   __restrict__ I,        // (B,M,O)
    float*       __restrict__ out)      // (B,M,F,K)
{
    __shared__ float s_logits[O_];
    __shared__ float s_W[O_ * K_];   // [o][k]: 2x ds_read_b128 broadcast per o

    const int t  = threadIdx.x;
    const int bm = blockIdx.x;           // b*M + m (no swizzle: inputs are L3-fit,
                                         // XCD swizzle costs when L3-resident)
    const int b  = bm >> 13;             // / M_

    const float inv_temp = 1.0f / expf(log_temp[0]);

    // ---- distance phase: 32 groups x 4 lanes, contiguous per-group access ----
    // lane l of group g reads float4 at element offset (j*4+l)*4: the 4 lanes
    // cover 64 contiguous bytes per j -> dense cache lines, each touched once.
    {
        const int g = t >> 2;   // candidate o (0..31 across the 2 waves)
        const int l = t & 3;    // lane within group
        const int idxg = I[(size_t)bm * O_ + g];
        const float4* yrow = (const float4*)(ye + (size_t)bm * E_);
        const float4* xrow = (const float4*)(xe + ((size_t)b * N_ + idxg) * E_);
        float acc = 0.f;
        #pragma unroll
        for (int j = 0; j < 8; ++j) {
            float4 yv = yrow[j * 4 + l];
            float4 xv = xrow[j * 4 + l];
            float d0 = xv.x - yv.x, d1 = xv.y - yv.y;
            float d2 = xv.z - yv.z, d3 = xv.w - yv.w;
            acc += d0 * d0 + d1 * d1 + d2 * d2 + d3 * d3;
        }
        acc += __shfl_xor(acc, 1);
        acc += __shfl_xor(acc, 2);
        if (l == 0) s_logits[g] = -acc * inv_temp;   // D / temperature
    }

    // ---- prefetch ALL 32 gathered x values (thread t owns f=t). ----
    // Irow is block-uniform -> SGPR loads. asm pins keep the loads HERE so
    // the gather latency hides under the softmax (r4: compiler sank/spilled).
    const int* Irow = I + (size_t)bm * O_;
    const float* xb = x + (size_t)b * (N_ * F_) + t;
    float xv[O_];
    #pragma unroll
    for (int o = 0; o < O_; ++o) {
        xv[o] = xb[(size_t)(Irow[o] * F_)];
    }
    #pragma unroll
    for (int o = 0; o < O_; ++o) {
        asm volatile("" : "+v"(xv[o]));   // keep live across softmax, no code
    }

    __syncthreads();   // s_logits ready

    // ---- K-step relaxed top-k softmax: wave 0, lanes 0..31 (one lane per o) ----
    if (t < O_) {
        float logit = s_logits[t];
        float wloc[K_];
        #pragma unroll
        for (int k = 0; k < K_; ++k) {
            float mx = logit;
            #pragma unroll
            for (int d = 16; d >= 1; d >>= 1) mx = fmaxf(mx, __shfl_xor(mx, d, 32));
            float sh = logit - mx;
            float ev = __expf(sh);
            float sm = ev;
            #pragma unroll
            for (int d = 16; d >= 1; d >>= 1) sm += __shfl_xor(sm, d, 32);
            // sh=0 at the max lane -> sm >= 1 exactly -> w <= 0 -> Taylor p <= 0
            // -> arg = GUARD - p > 0 always (no NaN branch with fast log).
            float w = sh - __logf(sm);
            float sample = __expf(w);
            wloc[k] = sample;
            // log1mexp(w), reference branch + guard semantics:
            //  w <  log(0.5): log1p(-exp(w)) == log(1 - sample), no cancellation
            //  w >= log(0.5): log(-expm1(w) + 1e-7), expm1 via deg-7 Taylor
            float p = w * (1.0f + w * (0.5f + w * (0.16666667f + w * (4.1666667e-2f
                    + w * (8.3333333e-3f + w * (1.3888889e-3f + w * 1.9841270e-4f))))));
            float arg = (w < LOG_HALF_F) ? (1.0f - sample) : (GUARD_F - p);
            logit += __logf(arg);
        }
        ((float4*)&s_W[t * K_])[0] = make_float4(wloc[0], wloc[1], wloc[2], wloc[3]);
        ((float4*)&s_W[t * K_])[1] = make_float4(wloc[4], wloc[5], wloc[6], wloc[7]);
    }
    __syncthreads();   // s_W ready

    // ---- aggregation: thread t owns f = t; W via LDS broadcast, x from regs ----
    {
        float acc[K_];
        #pragma unroll
        for (int k = 0; k < K_; ++k) acc[k] = 0.f;
        #pragma unroll
        for (int o = 0; o < O_; ++o) {
            const float4 w0 = ((const float4*)&s_W[o * K_])[0];
            const float4 w1 = ((const float4*)&s_W[o * K_])[1];
            const float xvo = xv[o];
            acc[0] = fmaf(xvo, w0.x, acc[0]);
            acc[1] = fmaf(xvo, w0.y, acc[1]);
            acc[2] = fmaf(xvo, w0.z, acc[2]);
            acc[3] = fmaf(xvo, w0.w, acc[3]);
            acc[4] = fmaf(xvo, w1.x, acc[4]);
            acc[5] = fmaf(xvo, w1.y, acc[5]);
            acc[6] = fmaf(xvo, w1.z, acc[6]);
            acc[7] = fmaf(xvo, w1.w, acc[7]);
        }
        // Plain cached stores: L2 merges the two strided 16B/lane store
        // instructions into full 64B lines -> writeback = output size exactly
        // (round 3 measured WRITE_SIZE == 131 MB). Nontemporal bypass gave
        // ~2x partial-line write amplification + washed the LLC (round 5/6).
        float* orow = out + ((size_t)bm * F_ + t) * K_;
        ((float4*)orow)[0] = make_float4(acc[0], acc[1], acc[2], acc[3]);
        ((float4*)orow)[1] = make_float4(acc[4], acc[5], acc[6], acc[7]);
    }
}

extern "C" void kernel_launch(void* const* d_in, const int* in_sizes, int n_in,
                              void* d_out, int out_size, void* d_ws, size_t ws_size,
                              hipStream_t stream) {
    const float* x        = (const float*)d_in[0];
    const float* xe       = (const float*)d_in[1];
    const float* ye       = (const float*)d_in[2];
    const float* log_temp = (const float*)d_in[3];
    const int*   I        = (const int*)d_in[4];
    float* out = (float*)d_out;

    dim3 grid(B_ * M_);
    dim3 block(128);
    hipLaunchKernelGGL(n3agg_kernel, grid, block, 0, stream,
                       x, xe, ye, log_temp, I, out);
}

// Round 8
// 147.097 us; speedup vs baseline: 3.1397x; 1.4442x over previous
//
#include <hip/hip_runtime.h>
#include <math.h>

// Shapes fixed by the reference's setup_inputs()
#define B_ 4
#define N_ 8192
#define M_ 8192
#define O_ 32
#define E_ 128
#define F_ 128
#define K_ 8

#define LOG_HALF_F (-0.6931471805599453f)
#define GUARD_F 1e-7f

typedef float f4v __attribute__((ext_vector_type(4)));

// One 128-thread block (2 waves) per (b, m) pair.
// __launch_bounds__(128, 6): 6 waves/EU -> 12 blocks/CU, VGPR cap ~84.
// DO NOT raise to (128,8): the 64-VGPR cap spills the pinned xv[32] array
// to scratch (+~1 GB of HBM traffic, 3x slowdown — measured round 6).
__global__ __launch_bounds__(128, 6) void n3agg_kernel(
    const float* __restrict__ x,        // (B,N,F)
    const float* __restrict__ xe,       // (B,N,E)
    const float* __restrict__ ye,       // (B,M,E)
    const float* __restrict__ log_temp, // (1,)
    const int*   __restrict__ I,        // (B,M,O)
    float*       __restrict__ out)      // (B,M,F,K)
{
    __shared__ float s_logits[O_];
    __shared__ float s_W[O_ * K_];     // [o][k]: 2x ds_read_b128 broadcast per o
    __shared__ float s_out[F_ * K_];   // 4 KiB staging for full-line output stores

    const int t  = threadIdx.x;
    const int bm = blockIdx.x;           // b*M + m
    const int b  = bm >> 13;             // / M_

    const float inv_temp = 1.0f / expf(log_temp[0]);

    // ---- distance phase: 32 groups x 4 lanes, contiguous per-group access ----
    // lane l of group g reads float4 at element offset (j*4+l)*4: the 4 lanes
    // cover 64 contiguous bytes per j -> dense cache lines, each touched once.
    {
        const int g = t >> 2;   // candidate o (0..31 across the 2 waves)
        const int l = t & 3;    // lane within group
        const int idxg = I[(size_t)bm * O_ + g];
        const float4* yrow = (const float4*)(ye + (size_t)bm * E_);
        const float4* xrow = (const float4*)(xe + ((size_t)b * N_ + idxg) * E_);
        float acc = 0.f;
        #pragma unroll
        for (int j = 0; j < 8; ++j) {
            float4 yv = yrow[j * 4 + l];
            float4 xv = xrow[j * 4 + l];
            float d0 = xv.x - yv.x, d1 = xv.y - yv.y;
            float d2 = xv.z - yv.z, d3 = xv.w - yv.w;
            acc += d0 * d0 + d1 * d1 + d2 * d2 + d3 * d3;
        }
        acc += __shfl_xor(acc, 1);
        acc += __shfl_xor(acc, 2);
        if (l == 0) s_logits[g] = -acc * inv_temp;   // D / temperature
    }

    // ---- prefetch ALL 32 gathered x values (thread t owns f=t). ----
    // Irow is block-uniform -> SGPR loads. asm pins keep the loads HERE so
    // the gather latency hides under the softmax.
    const int* Irow = I + (size_t)bm * O_;
    const float* xb = x + (size_t)b * (N_ * F_) + t;
    float xv[O_];
    #pragma unroll
    for (int o = 0; o < O_; ++o) {
        xv[o] = xb[(size_t)(Irow[o] * F_)];
    }
    #pragma unroll
    for (int o = 0; o < O_; ++o) {
        asm volatile("" : "+v"(xv[o]));   // keep live across softmax, no code
    }

    __syncthreads();   // s_logits ready

    // ---- K-step relaxed top-k softmax: wave 0, lanes 0..31 (one lane per o) ----
    if (t < O_) {
        float logit = s_logits[t];
        float wloc[K_];
        #pragma unroll
        for (int k = 0; k < K_; ++k) {
            float mx = logit;
            #pragma unroll
            for (int d = 16; d >= 1; d >>= 1) mx = fmaxf(mx, __shfl_xor(mx, d, 32));
            float sh = logit - mx;
            float ev = __expf(sh);
            float sm = ev;
            #pragma unroll
            for (int d = 16; d >= 1; d >>= 1) sm += __shfl_xor(sm, d, 32);
            // sh=0 at the max lane -> sm >= 1 exactly -> w <= 0 -> Taylor p <= 0
            // -> arg = GUARD - p > 0 always (no NaN branch with fast log).
            float w = sh - __logf(sm);
            float sample = __expf(w);
            wloc[k] = sample;
            // log1mexp(w), reference branch + guard semantics:
            //  w <  log(0.5): log1p(-exp(w)) == log(1 - sample), no cancellation
            //  w >= log(0.5): log(-expm1(w) + 1e-7), expm1 via deg-7 Taylor
            float p = w * (1.0f + w * (0.5f + w * (0.16666667f + w * (4.1666667e-2f
                    + w * (8.3333333e-3f + w * (1.3888889e-3f + w * 1.9841270e-4f))))));
            float arg = (w < LOG_HALF_F) ? (1.0f - sample) : (GUARD_F - p);
            logit += __logf(arg);
        }
        ((float4*)&s_W[t * K_])[0] = make_float4(wloc[0], wloc[1], wloc[2], wloc[3]);
        ((float4*)&s_W[t * K_])[1] = make_float4(wloc[4], wloc[5], wloc[6], wloc[7]);
    }
    __syncthreads();   // s_W ready

    // ---- aggregation: thread t owns f = t; W via LDS broadcast, x from regs ----
    {
        float acc[K_];
        #pragma unroll
        for (int k = 0; k < K_; ++k) acc[k] = 0.f;
        #pragma unroll
        for (int o = 0; o < O_; ++o) {
            const float4 w0 = ((const float4*)&s_W[o * K_])[0];
            const float4 w1 = ((const float4*)&s_W[o * K_])[1];
            const float xvo = xv[o];
            acc[0] = fmaf(xvo, w0.x, acc[0]);
            acc[1] = fmaf(xvo, w0.y, acc[1]);
            acc[2] = fmaf(xvo, w0.z, acc[2]);
            acc[3] = fmaf(xvo, w0.w, acc[3]);
            acc[4] = fmaf(xvo, w1.x, acc[4]);
            acc[5] = fmaf(xvo, w1.y, acc[5]);
            acc[6] = fmaf(xvo, w1.z, acc[6]);
            acc[7] = fmaf(xvo, w1.w, acc[7]);
        }
        // Stage through LDS so each global store instruction covers FULL 64B
        // lines (wave = 1 KiB contiguous). Round 7 measured the cost of
        // partial-line stores: plain = 3x write amplification + write-allocate
        // fetches; NT strided = 1.83x. Full-line NT = exact-size writes and
        // zero L2 pollution.
        ((float4*)&s_out[t * K_])[0] = make_float4(acc[0], acc[1], acc[2], acc[3]);
        ((float4*)&s_out[t * K_])[1] = make_float4(acc[4], acc[5], acc[6], acc[7]);
    }
    __syncthreads();   // s_out ready (cross-lane exchange)

    {
        // Block output chunk: out + bm*1024 floats (4 KiB contiguous).
        // Instruction 0: threads 0..127 cover elements [0,512); instr 1: [512,1024).
        const f4v* src = (const f4v*)s_out;
        f4v v0 = src[t];
        f4v v1 = src[128 + t];
        f4v* dst = (f4v*)(out + (size_t)bm * (F_ * K_));
        __builtin_nontemporal_store(v0, dst + t);
        __builtin_nontemporal_store(v1, dst + 128 + t);
    }
}

extern "C" void kernel_launch(void* const* d_in, const int* in_sizes, int n_in,
                              void* d_out, int out_size, void* d_ws, size_t ws_size,
                              hipStream_t stream) {
    const float* x        = (const float*)d_in[0];
    const float* xe       = (const float*)d_in[1];
    const float* ye       = (const float*)d_in[2];
    const float* log_temp = (const float*)d_in[3];
    const int*   I        = (const int*)d_in[4];
    float* out = (float*)d_out;

    dim3 grid(B_ * M_);
    dim3 block(128);
    hipLaunchKernelGGL(n3agg_kernel, grid, block, 0, stream,
                       x, xe, ye, log_temp, I, out);
}

// Round 9
// 142.955 us; speedup vs baseline: 3.2307x; 1.0290x over previous
//
#include <hip/hip_runtime.h>
#include <math.h>

// Shapes fixed by the reference's setup_inputs()
#define B_ 4
#define N_ 8192
#define M_ 8192
#define O_ 32
#define E_ 128
#define F_ 128
#define K_ 8

#define LOG_HALF_F (-0.6931471805599453f)
#define GUARD_F 1e-7f

typedef float f4v __attribute__((ext_vector_type(4)));

// One 128-thread block (2 waves) per (b, m) pair.
// __launch_bounds__(128, 6): 6 waves/EU -> 12 blocks/CU, VGPR cap ~84.
// DO NOT raise to (128,8): the 64-VGPR cap spills the pinned xv[32] array
// to scratch (+~1 GB of HBM traffic, 3x slowdown — measured round 6).
__global__ __launch_bounds__(128, 6) void n3agg_kernel(
    const float* __restrict__ x,        // (B,N,F)
    const float* __restrict__ xe,       // (B,N,E)
    const float* __restrict__ ye,       // (B,M,E)
    const float* __restrict__ log_temp, // (1,)
    const int*   __restrict__ I,        // (B,M,O)
    float*       __restrict__ out)      // (B,M,F,K)
{
    __shared__ float s_logits[O_];
    __shared__ float s_W[O_ * K_];     // [o][k]: 2x ds_read_b128 broadcast per o
    __shared__ float s_out[F_ * K_];   // 4 KiB staging for full-line output stores

    const int t  = threadIdx.x;
    // Batch->XCD-pair swizzle. Blocks dispatch round-robin to the 8 XCDs
    // (XCD = blockIdx.x % 8). Map XCD p to batch p/2, m-half p&1:
    // per-XCD gather hot set (that batch's x+xe) = 8.4 MB instead of all
    // four batches' 33.6 MB -> ~4x better L2 capacity hit rate on the
    // 1.07 GB gather stream. 32768 % 8 == 0 -> bijective. Consecutive
    // bid>>3 = consecutive m, so ye/I/out accesses stay contiguous.
    // (Round 6 tested this confounded with a VGPR-spill regression; this
    // is the clean single-change test on the round-8 structure.)
    const int bid = blockIdx.x;
    const int p   = bid & 7;
    const int bm  = ((p >> 1) << 13) | ((p & 1) << 12) | (bid >> 3);  // b*M + m
    const int b   = bm >> 13;            // / M_

    const float inv_temp = 1.0f / expf(log_temp[0]);

    // ---- distance phase: 32 groups x 4 lanes, contiguous per-group access ----
    // lane l of group g reads float4 at element offset (j*4+l)*4: the 4 lanes
    // cover 64 contiguous bytes per j -> dense cache lines, each touched once.
    {
        const int g = t >> 2;   // candidate o (0..31 across the 2 waves)
        const int l = t & 3;    // lane within group
        const int idxg = I[(size_t)bm * O_ + g];
        const float4* yrow = (const float4*)(ye + (size_t)bm * E_);
        const float4* xrow = (const float4*)(xe + ((size_t)b * N_ + idxg) * E_);
        float acc = 0.f;
        #pragma unroll
        for (int j = 0; j < 8; ++j) {
            float4 yv = yrow[j * 4 + l];
            float4 xv = xrow[j * 4 + l];
            float d0 = xv.x - yv.x, d1 = xv.y - yv.y;
            float d2 = xv.z - yv.z, d3 = xv.w - yv.w;
            acc += d0 * d0 + d1 * d1 + d2 * d2 + d3 * d3;
        }
        acc += __shfl_xor(acc, 1);
        acc += __shfl_xor(acc, 2);
        if (l == 0) s_logits[g] = -acc * inv_temp;   // D / temperature
    }

    // ---- prefetch ALL 32 gathered x values (thread t owns f=t). ----
    // Irow is block-uniform -> SGPR loads. asm pins keep the loads HERE so
    // the gather latency hides under the softmax.
    const int* Irow = I + (size_t)bm * O_;
    const float* xb = x + (size_t)b * (N_ * F_) + t;
    float xv[O_];
    #pragma unroll
    for (int o = 0; o < O_; ++o) {
        xv[o] = xb[(size_t)(Irow[o] * F_)];
    }
    #pragma unroll
    for (int o = 0; o < O_; ++o) {
        asm volatile("" : "+v"(xv[o]));   // keep live across softmax, no code
    }

    __syncthreads();   // s_logits ready

    // ---- K-step relaxed top-k softmax: wave 0, lanes 0..31 (one lane per o) ----
    if (t < O_) {
        float logit = s_logits[t];
        float wloc[K_];
        #pragma unroll
        for (int k = 0; k < K_; ++k) {
            float mx = logit;
            #pragma unroll
            for (int d = 16; d >= 1; d >>= 1) mx = fmaxf(mx, __shfl_xor(mx, d, 32));
            float sh = logit - mx;
            float ev = __expf(sh);
            float sm = ev;
            #pragma unroll
            for (int d = 16; d >= 1; d >>= 1) sm += __shfl_xor(sm, d, 32);
            // sh=0 at the max lane -> sm >= 1 exactly -> w <= 0 -> Taylor p <= 0
            // -> arg = GUARD - p > 0 always (no NaN branch with fast log).
            float w = sh - __logf(sm);
            float sample = __expf(w);
            wloc[k] = sample;
            // log1mexp(w), reference branch + guard semantics:
            //  w <  log(0.5): log1p(-exp(w)) == log(1 - sample), no cancellation
            //  w >= log(0.5): log(-expm1(w) + 1e-7), expm1 via deg-7 Taylor
            float p7 = w * (1.0f + w * (0.5f + w * (0.16666667f + w * (4.1666667e-2f
                     + w * (8.3333333e-3f + w * (1.3888889e-3f + w * 1.9841270e-4f))))));
            float arg = (w < LOG_HALF_F) ? (1.0f - sample) : (GUARD_F - p7);
            logit += __logf(arg);
        }
        ((float4*)&s_W[t * K_])[0] = make_float4(wloc[0], wloc[1], wloc[2], wloc[3]);
        ((float4*)&s_W[t * K_])[1] = make_float4(wloc[4], wloc[5], wloc[6], wloc[7]);
    }
    __syncthreads();   // s_W ready

    // ---- aggregation: thread t owns f = t; W via LDS broadcast, x from regs ----
    {
        float acc[K_];
        #pragma unroll
        for (int k = 0; k < K_; ++k) acc[k] = 0.f;
        #pragma unroll
        for (int o = 0; o < O_; ++o) {
            const float4 w0 = ((const float4*)&s_W[o * K_])[0];
            const float4 w1 = ((const float4*)&s_W[o * K_])[1];
            const float xvo = xv[o];
            acc[0] = fmaf(xvo, w0.x, acc[0]);
            acc[1] = fmaf(xvo, w0.y, acc[1]);
            acc[2] = fmaf(xvo, w0.z, acc[2]);
            acc[3] = fmaf(xvo, w0.w, acc[3]);
            acc[4] = fmaf(xvo, w1.x, acc[4]);
            acc[5] = fmaf(xvo, w1.y, acc[5]);
            acc[6] = fmaf(xvo, w1.z, acc[6]);
            acc[7] = fmaf(xvo, w1.w, acc[7]);
        }
        // Stage through LDS so each global store instruction covers full 64B
        // lines (wave = 1 KiB contiguous), then NT-store (no L2 allocation).
        // Measured: strided plain = 3x write amp + write-allocate fetches (r7);
        // strided NT = 1.83x (r5); full-line NT = 1.75x (r8) — best so far.
        ((float4*)&s_out[t * K_])[0] = make_float4(acc[0], acc[1], acc[2], acc[3]);
        ((float4*)&s_out[t * K_])[1] = make_float4(acc[4], acc[5], acc[6], acc[7]);
    }
    __syncthreads();   // s_out ready (cross-lane exchange)

    {
        // Block output chunk: out + bm*1024 floats (4 KiB contiguous).
        const f4v* src = (const f4v*)s_out;
        f4v v0 = src[t];
        f4v v1 = src[128 + t];
        f4v* dst = (f4v*)(out + (size_t)bm * (F_ * K_));
        __builtin_nontemporal_store(v0, dst + t);
        __builtin_nontemporal_store(v1, dst + 128 + t);
    }
}

extern "C" void kernel_launch(void* const* d_in, const int* in_sizes, int n_in,
                              void* d_out, int out_size, void* d_ws, size_t ws_size,
                              hipStream_t stream) {
    const float* x        = (const float*)d_in[0];
    const float* xe       = (const float*)d_in[1];
    const float* ye       = (const float*)d_in[2];
    const float* log_temp = (const float*)d_in[3];
    const int*   I        = (const int*)d_in[4];
    float* out = (float*)d_out;

    dim3 grid(B_ * M_);
    dim3 block(128);
    hipLaunchKernelGGL(n3agg_kernel, grid, block, 0, stream,
                       x, xe, ye, log_temp, I, out);
}